// Round 14
// baseline (194.202 us; speedup 1.0000x reference)
//
#include <hip/hip_runtime.h>
#include <math.h>

#define NN 20000
#define EE 320000
#define ETOT (EE + NN)   // 340000 edges incl. self loops
#define NSCAN ((NN + 1023) / 1024)   // 20 scan blocks
#define FILLB ((ETOT + 255) / 256)   // 1329 fill blocks

typedef unsigned short ushort_t;
typedef unsigned int uint_t;
typedef __attribute__((ext_vector_type(8))) short bf16x8;
typedef __attribute__((ext_vector_type(4))) float f32x4;

__device__ __forceinline__ ushort_t f2bf(float f) {
  union { float f; uint_t u; } v; v.f = f;
  uint_t r = v.u + 0x7FFF + ((v.u >> 16) & 1);   // RNE
  return (ushort_t)(r >> 16);
}
__device__ __forceinline__ float bf2f(uint_t hi16) {
  union { uint_t u; float f; } v; v.u = hi16 << 16;
  return v.f;
}
__device__ __forceinline__ uint_t pack2(float a, float b) {
  return (uint_t)f2bf(a) | ((uint_t)f2bf(b) << 16);
}
__device__ __forceinline__ void unpack8(uint4 u, float* x) {
  x[0] = bf2f(u.x & 0xFFFF); x[1] = bf2f(u.x >> 16);
  x[2] = bf2f(u.y & 0xFFFF); x[3] = bf2f(u.y >> 16);
  x[4] = bf2f(u.z & 0xFFFF); x[5] = bf2f(u.z >> 16);
  x[6] = bf2f(u.w & 0xFFFF); x[7] = bf2f(u.w >> 16);
}

// ---------------- CSR build ----------------
__global__ void deg_kernel(const int* __restrict__ ei, int* __restrict__ deg) {
  int e = blockIdx.x * 256 + threadIdx.x;
  if (e >= ETOT) return;
  int dst = (e < EE) ? ei[EE + e] : (e - EE);
  atomicAdd(&deg[dst], 1);
}

// phase 1: per-1024-block local exclusive scan; block total -> partials
__global__ __launch_bounds__(1024) void scan1_kernel(const int* __restrict__ deg,
                                                     int* __restrict__ rowptr,
                                                     int* __restrict__ partials) {
  __shared__ int wsum[16];
  const int tid = threadIdx.x;
  const int lane = tid & 63, wid = tid >> 6;
  int i = blockIdx.x * 1024 + tid;
  int v = (i < NN) ? deg[i] : 0;
  int x = v;
  #pragma unroll
  for (int off = 1; off < 64; off <<= 1) {
    int y = __shfl_up(x, off, 64);
    if (lane >= off) x += y;
  }
  if (lane == 63) wsum[wid] = x;
  __syncthreads();
  if (tid < 64) {
    int w = (tid < 16) ? wsum[tid] : 0;
    #pragma unroll
    for (int off = 1; off < 16; off <<= 1) {
      int y = __shfl_up(w, off, 64);
      if (lane >= off) w += y;
    }
    if (tid < 16) wsum[tid] = w;
  }
  __syncthreads();
  int incl = x + (wid > 0 ? wsum[wid - 1] : 0);
  if (i < NN) rowptr[i] = incl - v;          // block-local exclusive
  if (tid == 1023) partials[blockIdx.x] = incl;  // block total (raw)
}

// phase 2 (merged): each block wave-reduces partials[0..bid) -> offset; add + cursor.
// Block 0 also zero-fills the csr_src prefetch pad [ETOT, ETOT+64).
__global__ __launch_bounds__(1024) void scan3_kernel(int* __restrict__ rowptr,
                                                     const int* __restrict__ partials,
                                                     int* __restrict__ cursor,
                                                     int* __restrict__ csr_src) {
  __shared__ int off_s;
  int tid = threadIdx.x;
  if (blockIdx.x == 0 && tid < 64) csr_src[ETOT + tid] = 0;   // prefetch pad
  if (tid < 64) {
    int v = (tid < NSCAN && tid < (int)blockIdx.x) ? partials[tid] : 0;
    #pragma unroll
    for (int o = 32; o; o >>= 1) v += __shfl_xor(v, o, 64);
    if (tid == 0) off_s = v;
  }
  __syncthreads();
  int off = off_s;
  int i = blockIdx.x * 1024 + tid;
  if (i < NN) {
    int r = rowptr[i] + off;
    rowptr[i] = r;
    cursor[i] = r;
  }
  if (blockIdx.x == NSCAN - 1 && tid == 0) rowptr[NN] = off + partials[NSCAN - 1];
}

// ---------------- merged: CSR fill + layer-1 linear + weight conversion ------------
// Blocks [0,FILLB): CSR fill. [FILLB,FILLB+NN): lin1. [FILLB+NN,+576): W2/W3 -> bf16.
__global__ void fill_lin1_w2bf(const int* __restrict__ ei, int* __restrict__ cursor,
                               int* __restrict__ csr_src,
                               const float* __restrict__ x,
                               const float* __restrict__ Wl, const float* __restrict__ bl,
                               const float* __restrict__ Wr, const float* __restrict__ br,
                               ushort_t* __restrict__ xlr,
                               const float* __restrict__ W0, const float* __restrict__ W1,
                               const float* __restrict__ W2, const float* __restrict__ W3,
                               ushort_t* __restrict__ Wb) {
  if (blockIdx.x < FILLB) {
    int e = blockIdx.x * 256 + threadIdx.x;
    if (e >= ETOT) return;
    int src, dst;
    if (e < EE) { src = ei[e]; dst = ei[EE + e]; } else { src = dst = e - EE; }
    int slot = atomicAdd(&cursor[dst], 1);
    csr_src[slot] = src;
    return;
  }
  if (blockIdx.x >= FILLB + NN) {
    int i = (blockIdx.x - FILLB - NN) * 256 + threadIdx.x;   // 147456 total
    if (i < 65536) Wb[i] = f2bf(W0[i]);
    else if (i < 131072) Wb[i] = f2bf(W1[i - 65536]);
    else if (i < 139264) Wb[i] = f2bf(W2[i - 131072]);
    else if (i < 147456) Wb[i] = f2bf(W3[i - 139264]);
    return;
  }
  int n = blockIdx.x - FILLB, o = threadIdx.x;
  float4 xv = *reinterpret_cast<const float4*>(x + (size_t)n * 4);
  float4 wl = *reinterpret_cast<const float4*>(Wl + (size_t)o * 4);
  float4 wr = *reinterpret_cast<const float4*>(Wr + (size_t)o * 4);
  xlr[(size_t)n * 512 + o]       = f2bf(wl.x * xv.x + wl.y * xv.y + wl.z * xv.z + wl.w * xv.w + bl[o]);
  xlr[(size_t)n * 512 + 256 + o] = f2bf(wr.x * xv.x + wr.y * xv.y + wr.z * xv.z + wr.w * xv.w + br[o]);
}

// ---------------- MFMA bf16 GEMM: Y[M][N] = X[M][256] * W[N][256]^T + bias ---------
// Wave tile 64x64, swapped operands -> D[n][m], packed uint2 stores.
template<int N, int NL, int WMW, int WNW>
__global__ __launch_bounds__(WMW * WNW * 64) void gemm_mfma(
    const ushort_t* __restrict__ X, const ushort_t* __restrict__ Wb,
    const float* __restrict__ bl, const float* __restrict__ br,
    ushort_t* __restrict__ Y, int M) {
  const int wave = threadIdx.x >> 6;
  const int lane = threadIdx.x & 63;
  const int wm = wave / WNW, wn = wave % WNW;
  const int r16 = lane & 15;
  const int koff = (lane >> 4) * 8;
  const int m0 = blockIdx.x * (WMW * 64) + wm * 64;
  const int nb = blockIdx.y * (WNW * 64) + wn * 64;

  const ushort_t* xp = X + (size_t)(m0 + r16) * 256 + koff;
  const ushort_t* wp = Wb + (size_t)(nb + r16) * 256 + koff;

  f32x4 acc[4][4] = {};   // [j: n-frag][i: m-frag]
  bf16x8 A[4], B[4], An[4], Bn[4];
  #pragma unroll
  for (int i = 0; i < 4; ++i) {
    A[i] = *reinterpret_cast<const bf16x8*>(xp + i * 16 * 256);
    B[i] = *reinterpret_cast<const bf16x8*>(wp + i * 16 * 256);
  }
  #pragma unroll
  for (int t = 0; t < 8; ++t) {
    if (t < 7) {
      const int k0 = (t + 1) * 32;
      #pragma unroll
      for (int i = 0; i < 4; ++i) {
        An[i] = *reinterpret_cast<const bf16x8*>(xp + i * 16 * 256 + k0);
        Bn[i] = *reinterpret_cast<const bf16x8*>(wp + i * 16 * 256 + k0);
      }
    }
    #pragma unroll
    for (int j = 0; j < 4; ++j)
      #pragma unroll
      for (int i = 0; i < 4; ++i)
        acc[j][i] = __builtin_amdgcn_mfma_f32_16x16x32_bf16(B[j], A[i], acc[j][i], 0, 0, 0);
    #pragma unroll
    for (int i = 0; i < 4; ++i) { A[i] = An[i]; B[i] = Bn[i]; }
  }

  #pragma unroll
  for (int j = 0; j < 4; ++j) {
    const int ncol0 = nb + j * 16 + (lane >> 4) * 4;
    const float4 bv = *reinterpret_cast<const float4*>(
        (ncol0 < NL) ? (bl + ncol0) : (br + (ncol0 - NL)));
    #pragma unroll
    for (int i = 0; i < 4; ++i) {
      int m = m0 + i * 16 + r16;
      if (m < M) {
        uint2 o;
        o.x = pack2(acc[j][i][0] + bv.x, acc[j][i][1] + bv.y);
        o.y = pack2(acc[j][i][2] + bv.z, acc[j][i][3] + bv.w);
        *reinterpret_cast<uint2*>(Y + (size_t)m * N + ncol0) = o;
      }
    }
  }
}

// ---------------- fused GATv2 attention + aggregation, H=4, C=64 -------------------
// Input xlr[n][512] interleaved (xl at +0, xr at +256). Output hbuf[n][256] bf16.
// 4 nodes per block; wave per node; two 32-lane halves on alternate edges; lane owns
// 8 channels. Defer-max online softmax. 2-deep branch-free software pipeline:
// rows for edges s and s+2 held in registers, load for s+4 issued at loop top.
// Prefetch indices are unclamped — csr_src has a 64-entry zero pad past ETOT.
template<bool BN_ELU>
__global__ __launch_bounds__(256) void fused_agg4(
    const ushort_t* __restrict__ xlr,
    const int* __restrict__ rowptr, const int* __restrict__ csr_src,
    const float* __restrict__ att, const float* __restrict__ bias,
    const float* __restrict__ bn_g, const float* __restrict__ bn_b,
    const float* __restrict__ bn_m, const float* __restrict__ bn_v,
    ushort_t* __restrict__ out) {
  int n = blockIdx.x * 4 + (threadIdx.x >> 6);
  if (n >= NN) return;
  int lane = threadIdx.x & 63;
  int half = lane >> 5;       // which edge of each pair
  int l32 = lane & 31;        // owns channels [l32*8, l32*8+8)

  float xr[8], at[8];
  {
    uint4 xru = reinterpret_cast<const uint4*>(xlr + (size_t)n * 512 + 256)[l32];
    unpack8(xru, xr);
    float4 a0 = reinterpret_cast<const float4*>(att)[l32 * 2];
    float4 a1 = reinterpret_cast<const float4*>(att)[l32 * 2 + 1];
    at[0] = a0.x; at[1] = a0.y; at[2] = a0.z; at[3] = a0.w;
    at[4] = a1.x; at[5] = a1.y; at[6] = a1.z; at[7] = a1.w;
  }
  int beg = rowptr[n], end = rowptr[n + 1];

  float m = -3.4e38f, d = 0.f;
  float acc[8] = {0.f, 0.f, 0.f, 0.f, 0.f, 0.f, 0.f, 0.f};

  int s = beg + half;
  // branch-free prologue prefetch: s <= end <= ETOT, pad covers s..s+2
  uint4 xu0 = reinterpret_cast<const uint4*>(xlr + (size_t)csr_src[s] * 512)[l32];
  uint4 xu1 = reinterpret_cast<const uint4*>(xlr + (size_t)csr_src[s + 2] * 512)[l32];

  for (; s < end; s += 2) {
    // issue load for edge s+4 (pad-safe) before the serial tail of edge s
    uint4 xu2 = reinterpret_cast<const uint4*>(xlr + (size_t)csr_src[s + 4] * 512)[l32];

    float x[8];
    unpack8(xu0, x);
    float sc = 0.f;
    #pragma unroll
    for (int c = 0; c < 8; ++c) {
      float e = x[c] + xr[c];
      e = fmaxf(e, 0.2f * e);          // leaky_relu
      sc = fmaf(at[c], e, sc);
    }
    #pragma unroll
    for (int off = 4; off; off >>= 1) sc += __shfl_xor(sc, off, 64);  // 8-lane head sum
    if (__any(sc > m + 8.f)) {
      float mn = fmaxf(m, sc);
      float scl = __expf(m - mn);
      float w = __expf(sc - mn);
      #pragma unroll
      for (int c = 0; c < 8; ++c) acc[c] = fmaf(w, x[c], acc[c] * scl);
      d = d * scl + w;
      m = mn;
    } else {
      float w = __expf(sc - m);
      #pragma unroll
      for (int c = 0; c < 8; ++c) acc[c] = fmaf(w, x[c], acc[c]);
      d += w;
    }
    xu0 = xu1;
    xu1 = xu2;
  }

  // merge the two half-states (half0 always non-empty: self-loop => deg>=1)
  {
    float mo = __shfl_xor(m, 32, 64);
    float doo = __shfl_xor(d, 32, 64);
    float ao[8];
    #pragma unroll
    for (int c = 0; c < 8; ++c) ao[c] = __shfl_xor(acc[c], 32, 64);
    if (doo > 0.f) {
      if (d > 0.f) {
        float mn = fmaxf(m, mo);
        float se = __expf(m - mn), so = __expf(mo - mn);
        #pragma unroll
        for (int c = 0; c < 8; ++c) acc[c] = acc[c] * se + ao[c] * so;
        d = d * se + doo * so;
      } else {
        #pragma unroll
        for (int c = 0; c < 8; ++c) acc[c] = ao[c];
        d = doo;
      }
    }
  }

  if (half == 0) {
    float inv = 1.f / (d + 1e-16f);
    float4 b0 = reinterpret_cast<const float4*>(bias)[l32 * 2];
    float4 b1 = reinterpret_cast<const float4*>(bias)[l32 * 2 + 1];
    float v[8];
    v[0] = acc[0] * inv + b0.x; v[1] = acc[1] * inv + b0.y;
    v[2] = acc[2] * inv + b0.z; v[3] = acc[3] * inv + b0.w;
    v[4] = acc[4] * inv + b1.x; v[5] = acc[5] * inv + b1.y;
    v[6] = acc[6] * inv + b1.z; v[7] = acc[7] * inv + b1.w;
    if (BN_ELU) {
      float4 g0 = reinterpret_cast<const float4*>(bn_g)[l32 * 2];
      float4 g1 = reinterpret_cast<const float4*>(bn_g)[l32 * 2 + 1];
      float4 bb0 = reinterpret_cast<const float4*>(bn_b)[l32 * 2];
      float4 bb1 = reinterpret_cast<const float4*>(bn_b)[l32 * 2 + 1];
      float4 mu0 = reinterpret_cast<const float4*>(bn_m)[l32 * 2];
      float4 mu1 = reinterpret_cast<const float4*>(bn_m)[l32 * 2 + 1];
      float4 va0 = reinterpret_cast<const float4*>(bn_v)[l32 * 2];
      float4 va1 = reinterpret_cast<const float4*>(bn_v)[l32 * 2 + 1];
      float g[8] = {g0.x, g0.y, g0.z, g0.w, g1.x, g1.y, g1.z, g1.w};
      float bb[8] = {bb0.x, bb0.y, bb0.z, bb0.w, bb1.x, bb1.y, bb1.z, bb1.w};
      float mu[8] = {mu0.x, mu0.y, mu0.z, mu0.w, mu1.x, mu1.y, mu1.z, mu1.w};
      float va[8] = {va0.x, va0.y, va0.z, va0.w, va1.x, va1.y, va1.z, va1.w};
      #pragma unroll
      for (int c = 0; c < 8; ++c) {
        float sc = g[c] * rsqrtf(va[c] + 1e-5f);
        float t = sc * (v[c] - mu[c]) + bb[c];
        v[c] = (t > 0.f) ? t : expm1f(t);
      }
    }
    uint4 o;
    o.x = pack2(v[0], v[1]);
    o.y = pack2(v[2], v[3]);
    o.z = pack2(v[4], v[5]);
    o.w = pack2(v[6], v[7]);
    reinterpret_cast<uint4*>(out + (size_t)n * 256)[l32] = o;
  }
}

// ---------------- fused layer 3: H=1, C=32, bias only ------------------------------
// Input xlr[n][64] interleaved. 4 nodes/block; wave/node; 16 lanes per edge,
// 4 edges in flight; 1-deep branch-free load pipeline (pad-safe prefetch).
__global__ __launch_bounds__(256) void fused_agg3(
    const ushort_t* __restrict__ xlr,
    const int* __restrict__ rowptr, const int* __restrict__ csr_src,
    const float* __restrict__ att, const float* __restrict__ bias,
    float* __restrict__ out) {
  int n = blockIdx.x * 4 + (threadIdx.x >> 6);
  if (n >= NN) return;
  int lane = threadIdx.x & 63;
  int grp = lane >> 4;        // which of 4 edges in flight
  int cl = lane & 15;         // channel pair index
  uint_t xru = reinterpret_cast<const uint_t*>(xlr + (size_t)n * 64 + 32)[cl];
  float xr0 = bf2f(xru & 0xFFFF), xr1 = bf2f(xru >> 16);
  float2 atv = reinterpret_cast<const float2*>(att)[cl];
  int beg = rowptr[n], end = rowptr[n + 1];
  float m = -3.4e38f, d = 0.f, a0 = 0.f, a1 = 0.f;

  int s = beg + grp;
  uint_t xu = reinterpret_cast<const uint_t*>(xlr + (size_t)csr_src[s] * 64)[cl];

  for (; s < end; s += 4) {
    uint_t xun = reinterpret_cast<const uint_t*>(xlr + (size_t)csr_src[s + 4] * 64)[cl];

    float x0 = bf2f(xu & 0xFFFF), x1 = bf2f(xu >> 16);
    float e0 = x0 + xr0; e0 = fmaxf(e0, 0.2f * e0);
    float e1 = x1 + xr1; e1 = fmaxf(e1, 0.2f * e1);
    float sc = fmaf(atv.x, e0, atv.y * e1);
    #pragma unroll
    for (int off = 8; off; off >>= 1) sc += __shfl_xor(sc, off, 64);  // 16-lane sum
    if (__any(sc > m + 8.f)) {
      float mn = fmaxf(m, sc);
      float scale = __expf(m - mn);
      float w = __expf(sc - mn);
      a0 = fmaf(w, x0, a0 * scale);
      a1 = fmaf(w, x1, a1 * scale);
      d = d * scale + w;
      m = mn;
    } else {
      float w = __expf(sc - m);
      a0 = fmaf(w, x0, a0);
      a1 = fmaf(w, x1, a1);
      d += w;
    }
    xu = xun;
  }
  // merge the 4 per-group online states (some may be empty; guard via d)
  #pragma unroll
  for (int off = 16; off <= 32; off <<= 1) {
    float mo = __shfl_xor(m, off, 64);
    float doo = __shfl_xor(d, off, 64);
    float c0 = __shfl_xor(a0, off, 64);
    float c1 = __shfl_xor(a1, off, 64);
    if (doo > 0.f) {
      if (d > 0.f) {
        float mn = fmaxf(m, mo);
        float se = __expf(m - mn), so = __expf(mo - mn);
        a0 = a0 * se + c0 * so;
        a1 = a1 * se + c1 * so;
        d = d * se + doo * so;
        m = mn;
      } else {
        a0 = c0; a1 = c1; d = doo; m = mo;
      }
    }
  }
  if (grp == 0) {
    float inv = 1.f / (d + 1e-16f);
    float2 bsv = reinterpret_cast<const float2*>(bias)[cl];
    reinterpret_cast<float2*>(out + (size_t)n * 32)[cl] =
        make_float2(a0 * inv + bsv.x, a1 * inv + bsv.y);
  }
}

extern "C" void kernel_launch(void* const* d_in, const int* in_sizes, int n_in,
                              void* d_out, int out_size, void* d_ws, size_t ws_size,
                              hipStream_t stream) {
  (void)in_sizes; (void)n_in; (void)out_size; (void)ws_size;
  const float* x  = (const float*)d_in[0];
  const int*   ei = (const int*)d_in[1];
  const float *Wl1 = (const float*)d_in[2],  *bl1 = (const float*)d_in[3],
              *Wr1 = (const float*)d_in[4],  *br1 = (const float*)d_in[5],
              *att1 = (const float*)d_in[6], *bias1 = (const float*)d_in[7],
              *g1 = (const float*)d_in[8],   *be1 = (const float*)d_in[9],
              *m1 = (const float*)d_in[10],  *v1 = (const float*)d_in[11];
  const float *Wl2 = (const float*)d_in[12], *bl2 = (const float*)d_in[13],
              *Wr2 = (const float*)d_in[14], *br2 = (const float*)d_in[15],
              *att2 = (const float*)d_in[16], *bias2 = (const float*)d_in[17],
              *g2 = (const float*)d_in[18],  *be2 = (const float*)d_in[19],
              *m2 = (const float*)d_in[20],  *v2 = (const float*)d_in[21];
  const float *Wl3 = (const float*)d_in[22], *bl3 = (const float*)d_in[23],
              *Wr3 = (const float*)d_in[24], *br3 = (const float*)d_in[25],
              *att3 = (const float*)d_in[26], *bias3 = (const float*)d_in[27];
  float* out = (float*)d_out;

  char* p = (char*)d_ws;
  auto alloc = [&](size_t bytes) { char* r = p; p += (bytes + 255) & ~(size_t)255; return r; };
  int*      deg      = (int*)alloc((size_t)NN * 4);
  int*      rowptr   = (int*)alloc((size_t)(NN + 1) * 4);
  int*      cursor   = (int*)alloc((size_t)NN * 4);
  int*      partials = (int*)alloc((size_t)NSCAN * 4);
  int*      csr_src  = (int*)alloc((size_t)(ETOT + 64) * 4);   // +64 prefetch pad
  ushort_t* xlr      = (ushort_t*)alloc((size_t)NN * 512 * 2); // interleaved xl|xr
  ushort_t* hbuf     = (ushort_t*)alloc((size_t)NN * 256 * 2);
  ushort_t* Wb       = (ushort_t*)alloc((size_t)147456 * 2);
  (void)alloc(262144);                                         // tail slack (OOB-read room)

  // CSR by dst (2-phase parallel scan)
  hipMemsetAsync(deg, 0, (size_t)NN * 4, stream);
  deg_kernel<<<(ETOT + 255) / 256, 256, 0, stream>>>(ei, deg);
  scan1_kernel<<<NSCAN, 1024, 0, stream>>>(deg, rowptr, partials);
  scan3_kernel<<<NSCAN, 1024, 0, stream>>>(rowptr, partials, cursor, csr_src);

  int nb = (NN + 3) / 4;

  // ---- CSR fill + layer-1 linear + W2/W3 bf16 conversion (one kernel) ----
  fill_lin1_w2bf<<<FILLB + NN + 576, 256, 0, stream>>>(
      ei, cursor, csr_src, x, Wl1, bl1, Wr1, br1, xlr, Wl2, Wr2, Wl3, Wr3, Wb);
  fused_agg4<true><<<nb, 256, 0, stream>>>(xlr, rowptr, csr_src, att1, bias1,
                                           g1, be1, m1, v1, hbuf);

  // ---- layer 2: 256 -> 4x64 concat (l and r in one N=512 GEMM), BN+ELU ----
  {
    dim3 g((NN + 63) / 64, 2);   // block tile 64 rows x 256 cols (4 waves on N)
    gemm_mfma<512, 256, 1, 4><<<g, 256, 0, stream>>>(hbuf, Wb, bl2, br2, xlr, NN);
  }
  fused_agg4<true><<<nb, 256, 0, stream>>>(xlr, rowptr, csr_src, att2, bias2,
                                           g2, be2, m2, v2, hbuf);

  // ---- layer 3: 256 -> 32, 1 head (l and r in one N=64 GEMM) ----
  {
    dim3 g((NN + 255) / 256, 1); // block tile 256 rows x 64 cols (4 waves on M)
    gemm_mfma<64, 32, 4, 1><<<g, 256, 0, stream>>>(hbuf, Wb + 131072, bl3, br3, xlr, NN);
  }
  fused_agg3<<<nb, 256, 0, stream>>>(xlr, rowptr, csr_src, att3, bias3, out);
}

// Round 15
// 178.573 us; speedup vs baseline: 1.0875x; 1.0875x over previous
//
#include <hip/hip_runtime.h>
#include <math.h>

#define NN 20000
#define EE 320000
#define ETOT (EE + NN)   // 340000 edges incl. self loops
#define NSCAN ((NN + 1023) / 1024)   // 20 scan blocks
#define FILLB ((ETOT + 255) / 256)   // 1329 fill blocks

typedef unsigned short ushort_t;
typedef unsigned int uint_t;
typedef __attribute__((ext_vector_type(8))) short bf16x8;
typedef __attribute__((ext_vector_type(4))) float f32x4;

__device__ __forceinline__ ushort_t f2bf(float f) {
  union { float f; uint_t u; } v; v.f = f;
  uint_t r = v.u + 0x7FFF + ((v.u >> 16) & 1);   // RNE
  return (ushort_t)(r >> 16);
}
__device__ __forceinline__ float bf2f(uint_t hi16) {
  union { uint_t u; float f; } v; v.u = hi16 << 16;
  return v.f;
}
__device__ __forceinline__ uint_t pack2(float a, float b) {
  return (uint_t)f2bf(a) | ((uint_t)f2bf(b) << 16);
}
__device__ __forceinline__ void unpack8(uint4 u, float* x) {
  x[0] = bf2f(u.x & 0xFFFF); x[1] = bf2f(u.x >> 16);
  x[2] = bf2f(u.y & 0xFFFF); x[3] = bf2f(u.y >> 16);
  x[4] = bf2f(u.z & 0xFFFF); x[5] = bf2f(u.z >> 16);
  x[6] = bf2f(u.w & 0xFFFF); x[7] = bf2f(u.w >> 16);
}

// ---------------- CSR build ----------------
__global__ void deg_kernel(const int* __restrict__ ei, int* __restrict__ deg) {
  int e = blockIdx.x * 256 + threadIdx.x;
  if (e >= ETOT) return;
  int dst = (e < EE) ? ei[EE + e] : (e - EE);
  atomicAdd(&deg[dst], 1);
}

// phase 1: per-1024-block local exclusive scan; block total -> partials
__global__ __launch_bounds__(1024) void scan1_kernel(const int* __restrict__ deg,
                                                     int* __restrict__ rowptr,
                                                     int* __restrict__ partials) {
  __shared__ int wsum[16];
  const int tid = threadIdx.x;
  const int lane = tid & 63, wid = tid >> 6;
  int i = blockIdx.x * 1024 + tid;
  int v = (i < NN) ? deg[i] : 0;
  int x = v;
  #pragma unroll
  for (int off = 1; off < 64; off <<= 1) {
    int y = __shfl_up(x, off, 64);
    if (lane >= off) x += y;
  }
  if (lane == 63) wsum[wid] = x;
  __syncthreads();
  if (tid < 64) {
    int w = (tid < 16) ? wsum[tid] : 0;
    #pragma unroll
    for (int off = 1; off < 16; off <<= 1) {
      int y = __shfl_up(w, off, 64);
      if (lane >= off) w += y;
    }
    if (tid < 16) wsum[tid] = w;
  }
  __syncthreads();
  int incl = x + (wid > 0 ? wsum[wid - 1] : 0);
  if (i < NN) rowptr[i] = incl - v;          // block-local exclusive
  if (tid == 1023) partials[blockIdx.x] = incl;  // block total (raw)
}

// phase 2 (merged): each block wave-reduces partials[0..bid) -> offset; add + cursor
__global__ __launch_bounds__(1024) void scan3_kernel(int* __restrict__ rowptr,
                                                     const int* __restrict__ partials,
                                                     int* __restrict__ cursor) {
  __shared__ int off_s;
  int tid = threadIdx.x;
  if (tid < 64) {
    int v = (tid < NSCAN && tid < (int)blockIdx.x) ? partials[tid] : 0;
    #pragma unroll
    for (int o = 32; o; o >>= 1) v += __shfl_xor(v, o, 64);
    if (tid == 0) off_s = v;
  }
  __syncthreads();
  int off = off_s;
  int i = blockIdx.x * 1024 + tid;
  if (i < NN) {
    int r = rowptr[i] + off;
    rowptr[i] = r;
    cursor[i] = r;
  }
  if (blockIdx.x == NSCAN - 1 && tid == 0) rowptr[NN] = off + partials[NSCAN - 1];
}

// ---------------- merged: CSR fill + layer-1 linear + weight conversion ------------
// Blocks [0,FILLB): CSR fill. [FILLB,FILLB+NN): lin1. [FILLB+NN,+576): W2/W3 -> bf16.
__global__ void fill_lin1_w2bf(const int* __restrict__ ei, int* __restrict__ cursor,
                               int* __restrict__ csr_src,
                               const float* __restrict__ x,
                               const float* __restrict__ Wl, const float* __restrict__ bl,
                               const float* __restrict__ Wr, const float* __restrict__ br,
                               ushort_t* __restrict__ xlr,
                               const float* __restrict__ W0, const float* __restrict__ W1,
                               const float* __restrict__ W2, const float* __restrict__ W3,
                               ushort_t* __restrict__ Wb) {
  if (blockIdx.x < FILLB) {
    int e = blockIdx.x * 256 + threadIdx.x;
    if (e >= ETOT) return;
    int src, dst;
    if (e < EE) { src = ei[e]; dst = ei[EE + e]; } else { src = dst = e - EE; }
    int slot = atomicAdd(&cursor[dst], 1);
    csr_src[slot] = src;
    return;
  }
  if (blockIdx.x >= FILLB + NN) {
    int i = (blockIdx.x - FILLB - NN) * 256 + threadIdx.x;   // 147456 total
    if (i < 65536) Wb[i] = f2bf(W0[i]);
    else if (i < 131072) Wb[i] = f2bf(W1[i - 65536]);
    else if (i < 139264) Wb[i] = f2bf(W2[i - 131072]);
    else if (i < 147456) Wb[i] = f2bf(W3[i - 139264]);
    return;
  }
  int n = blockIdx.x - FILLB, o = threadIdx.x;
  float4 xv = *reinterpret_cast<const float4*>(x + (size_t)n * 4);
  float4 wl = *reinterpret_cast<const float4*>(Wl + (size_t)o * 4);
  float4 wr = *reinterpret_cast<const float4*>(Wr + (size_t)o * 4);
  xlr[(size_t)n * 512 + o]       = f2bf(wl.x * xv.x + wl.y * xv.y + wl.z * xv.z + wl.w * xv.w + bl[o]);
  xlr[(size_t)n * 512 + 256 + o] = f2bf(wr.x * xv.x + wr.y * xv.y + wr.z * xv.z + wr.w * xv.w + br[o]);
}

// ---------------- MFMA bf16 GEMM: Y[M][N] = X[M][256] * W[N][256]^T + bias ---------
// Wave tile 64x64, swapped operands -> D[n][m], packed uint2 stores.
template<int N, int NL, int WMW, int WNW>
__global__ __launch_bounds__(WMW * WNW * 64) void gemm_mfma(
    const ushort_t* __restrict__ X, const ushort_t* __restrict__ Wb,
    const float* __restrict__ bl, const float* __restrict__ br,
    ushort_t* __restrict__ Y, int M) {
  const int wave = threadIdx.x >> 6;
  const int lane = threadIdx.x & 63;
  const int wm = wave / WNW, wn = wave % WNW;
  const int r16 = lane & 15;
  const int koff = (lane >> 4) * 8;
  const int m0 = blockIdx.x * (WMW * 64) + wm * 64;
  const int nb = blockIdx.y * (WNW * 64) + wn * 64;

  const ushort_t* xp = X + (size_t)(m0 + r16) * 256 + koff;
  const ushort_t* wp = Wb + (size_t)(nb + r16) * 256 + koff;

  f32x4 acc[4][4] = {};   // [j: n-frag][i: m-frag]
  bf16x8 A[4], B[4], An[4], Bn[4];
  #pragma unroll
  for (int i = 0; i < 4; ++i) {
    A[i] = *reinterpret_cast<const bf16x8*>(xp + i * 16 * 256);
    B[i] = *reinterpret_cast<const bf16x8*>(wp + i * 16 * 256);
  }
  #pragma unroll
  for (int t = 0; t < 8; ++t) {
    if (t < 7) {
      const int k0 = (t + 1) * 32;
      #pragma unroll
      for (int i = 0; i < 4; ++i) {
        An[i] = *reinterpret_cast<const bf16x8*>(xp + i * 16 * 256 + k0);
        Bn[i] = *reinterpret_cast<const bf16x8*>(wp + i * 16 * 256 + k0);
      }
    }
    #pragma unroll
    for (int j = 0; j < 4; ++j)
      #pragma unroll
      for (int i = 0; i < 4; ++i)
        acc[j][i] = __builtin_amdgcn_mfma_f32_16x16x32_bf16(B[j], A[i], acc[j][i], 0, 0, 0);
    #pragma unroll
    for (int i = 0; i < 4; ++i) { A[i] = An[i]; B[i] = Bn[i]; }
  }

  #pragma unroll
  for (int j = 0; j < 4; ++j) {
    const int ncol0 = nb + j * 16 + (lane >> 4) * 4;
    const float4 bv = *reinterpret_cast<const float4*>(
        (ncol0 < NL) ? (bl + ncol0) : (br + (ncol0 - NL)));
    #pragma unroll
    for (int i = 0; i < 4; ++i) {
      int m = m0 + i * 16 + r16;
      if (m < M) {
        uint2 o;
        o.x = pack2(acc[j][i][0] + bv.x, acc[j][i][1] + bv.y);
        o.y = pack2(acc[j][i][2] + bv.z, acc[j][i][3] + bv.w);
        *reinterpret_cast<uint2*>(Y + (size_t)m * N + ncol0) = o;
      }
    }
  }
}

// ---------------- fused GATv2 attention + aggregation, H=4, C=64 -------------------
// Input xlr[n][512] interleaved (xl at +0, xr at +256). Output hbuf[n][256] bf16.
// 4 nodes per block; wave per node; two 32-lane halves on alternate edges; lane owns
// 8 channels. Defer-max online softmax. Decoupled pipeline: row prefetch 1-deep
// (clamped), INDEX prefetch 2-deep — the row load at iteration top uses an index
// loaded one iteration earlier, removing the idx->row serial chain.
template<bool BN_ELU>
__global__ __launch_bounds__(256) void fused_agg4(
    const ushort_t* __restrict__ xlr,
    const int* __restrict__ rowptr, const int* __restrict__ csr_src,
    const float* __restrict__ att, const float* __restrict__ bias,
    const float* __restrict__ bn_g, const float* __restrict__ bn_b,
    const float* __restrict__ bn_m, const float* __restrict__ bn_v,
    ushort_t* __restrict__ out) {
  int n = blockIdx.x * 4 + (threadIdx.x >> 6);
  if (n >= NN) return;
  int lane = threadIdx.x & 63;
  int half = lane >> 5;       // which edge of each pair
  int l32 = lane & 31;        // owns channels [l32*8, l32*8+8)

  float xr[8], at[8];
  {
    uint4 xru = reinterpret_cast<const uint4*>(xlr + (size_t)n * 512 + 256)[l32];
    unpack8(xru, xr);
    float4 a0 = reinterpret_cast<const float4*>(att)[l32 * 2];
    float4 a1 = reinterpret_cast<const float4*>(att)[l32 * 2 + 1];
    at[0] = a0.x; at[1] = a0.y; at[2] = a0.z; at[3] = a0.w;
    at[4] = a1.x; at[5] = a1.y; at[6] = a1.z; at[7] = a1.w;
  }
  int beg = rowptr[n], end = rowptr[n + 1];
  const int e1 = end - 1;     // deg>=1 (self-loop) => e1 >= beg

  float m = -3.4e38f, d = 0.f;
  float acc[8] = {0.f, 0.f, 0.f, 0.f, 0.f, 0.f, 0.f, 0.f};

  int s = beg + half;
  // prologue: index for current edge + index for next edge, row for current edge
  int idxc = csr_src[(s < end) ? s : e1];
  int idxn = csr_src[(s + 2 < end) ? (s + 2) : e1];
  uint4 xu = reinterpret_cast<const uint4*>(xlr + (size_t)idxc * 512)[l32];

  for (; s < end; s += 2) {
    // index for edge s+4 (independent) and row for edge s+2 (index already resident)
    int idx2 = csr_src[(s + 4 < end) ? (s + 4) : e1];
    uint4 xun = reinterpret_cast<const uint4*>(xlr + (size_t)idxn * 512)[l32];

    float x[8];
    unpack8(xu, x);
    float sc = 0.f;
    #pragma unroll
    for (int c = 0; c < 8; ++c) {
      float e = x[c] + xr[c];
      e = fmaxf(e, 0.2f * e);          // leaky_relu
      sc = fmaf(at[c], e, sc);
    }
    #pragma unroll
    for (int off = 4; off; off >>= 1) sc += __shfl_xor(sc, off, 64);  // 8-lane head sum
    if (__any(sc > m + 8.f)) {
      float mn = fmaxf(m, sc);
      float scl = __expf(m - mn);
      float w = __expf(sc - mn);
      #pragma unroll
      for (int c = 0; c < 8; ++c) acc[c] = fmaf(w, x[c], acc[c] * scl);
      d = d * scl + w;
      m = mn;
    } else {
      float w = __expf(sc - m);
      #pragma unroll
      for (int c = 0; c < 8; ++c) acc[c] = fmaf(w, x[c], acc[c]);
      d += w;
    }
    xu = xun;
    idxn = idx2;
  }

  // merge the two half-states (half0 always non-empty: self-loop => deg>=1)
  {
    float mo = __shfl_xor(m, 32, 64);
    float doo = __shfl_xor(d, 32, 64);
    float ao[8];
    #pragma unroll
    for (int c = 0; c < 8; ++c) ao[c] = __shfl_xor(acc[c], 32, 64);
    if (doo > 0.f) {
      if (d > 0.f) {
        float mn = fmaxf(m, mo);
        float se = __expf(m - mn), so = __expf(mo - mn);
        #pragma unroll
        for (int c = 0; c < 8; ++c) acc[c] = acc[c] * se + ao[c] * so;
        d = d * se + doo * so;
      } else {
        #pragma unroll
        for (int c = 0; c < 8; ++c) acc[c] = ao[c];
        d = doo;
      }
    }
  }

  if (half == 0) {
    float inv = 1.f / (d + 1e-16f);
    float4 b0 = reinterpret_cast<const float4*>(bias)[l32 * 2];
    float4 b1 = reinterpret_cast<const float4*>(bias)[l32 * 2 + 1];
    float v[8];
    v[0] = acc[0] * inv + b0.x; v[1] = acc[1] * inv + b0.y;
    v[2] = acc[2] * inv + b0.z; v[3] = acc[3] * inv + b0.w;
    v[4] = acc[4] * inv + b1.x; v[5] = acc[5] * inv + b1.y;
    v[6] = acc[6] * inv + b1.z; v[7] = acc[7] * inv + b1.w;
    if (BN_ELU) {
      float4 g0 = reinterpret_cast<const float4*>(bn_g)[l32 * 2];
      float4 g1 = reinterpret_cast<const float4*>(bn_g)[l32 * 2 + 1];
      float4 bb0 = reinterpret_cast<const float4*>(bn_b)[l32 * 2];
      float4 bb1 = reinterpret_cast<const float4*>(bn_b)[l32 * 2 + 1];
      float4 mu0 = reinterpret_cast<const float4*>(bn_m)[l32 * 2];
      float4 mu1 = reinterpret_cast<const float4*>(bn_m)[l32 * 2 + 1];
      float4 va0 = reinterpret_cast<const float4*>(bn_v)[l32 * 2];
      float4 va1 = reinterpret_cast<const float4*>(bn_v)[l32 * 2 + 1];
      float g[8] = {g0.x, g0.y, g0.z, g0.w, g1.x, g1.y, g1.z, g1.w};
      float bb[8] = {bb0.x, bb0.y, bb0.z, bb0.w, bb1.x, bb1.y, bb1.z, bb1.w};
      float mu[8] = {mu0.x, mu0.y, mu0.z, mu0.w, mu1.x, mu1.y, mu1.z, mu1.w};
      float va[8] = {va0.x, va0.y, va0.z, va0.w, va1.x, va1.y, va1.z, va1.w};
      #pragma unroll
      for (int c = 0; c < 8; ++c) {
        float sc = g[c] * rsqrtf(va[c] + 1e-5f);
        float t = sc * (v[c] - mu[c]) + bb[c];
        v[c] = (t > 0.f) ? t : expm1f(t);
      }
    }
    uint4 o;
    o.x = pack2(v[0], v[1]);
    o.y = pack2(v[2], v[3]);
    o.z = pack2(v[4], v[5]);
    o.w = pack2(v[6], v[7]);
    reinterpret_cast<uint4*>(out + (size_t)n * 256)[l32] = o;
  }
}

// ---------------- fused layer 3: H=1, C=32, bias only ------------------------------
// Input xlr[n][64] interleaved. 4 nodes/block; wave/node; 16 lanes per edge,
// 4 edges in flight; decoupled 1-deep row / 2-deep index pipeline (clamped).
__global__ __launch_bounds__(256) void fused_agg3(
    const ushort_t* __restrict__ xlr,
    const int* __restrict__ rowptr, const int* __restrict__ csr_src,
    const float* __restrict__ att, const float* __restrict__ bias,
    float* __restrict__ out) {
  int n = blockIdx.x * 4 + (threadIdx.x >> 6);
  if (n >= NN) return;
  int lane = threadIdx.x & 63;
  int grp = lane >> 4;        // which of 4 edges in flight
  int cl = lane & 15;         // channel pair index
  uint_t xru = reinterpret_cast<const uint_t*>(xlr + (size_t)n * 64 + 32)[cl];
  float xr0 = bf2f(xru & 0xFFFF), xr1 = bf2f(xru >> 16);
  float2 atv = reinterpret_cast<const float2*>(att)[cl];
  int beg = rowptr[n], end = rowptr[n + 1];
  const int e1 = end - 1;
  float m = -3.4e38f, d = 0.f, a0 = 0.f, a1 = 0.f;

  int s = beg + grp;
  int idxc = csr_src[(s < end) ? s : e1];
  int idxn = csr_src[(s + 4 < end) ? (s + 4) : e1];
  uint_t xu = reinterpret_cast<const uint_t*>(xlr + (size_t)idxc * 64)[cl];

  for (; s < end; s += 4) {
    int idx2 = csr_src[(s + 8 < end) ? (s + 8) : e1];
    uint_t xun = reinterpret_cast<const uint_t*>(xlr + (size_t)idxn * 64)[cl];

    float x0 = bf2f(xu & 0xFFFF), x1 = bf2f(xu >> 16);
    float e0 = x0 + xr0; e0 = fmaxf(e0, 0.2f * e0);
    float e1f = x1 + xr1; e1f = fmaxf(e1f, 0.2f * e1f);
    float sc = fmaf(atv.x, e0, atv.y * e1f);
    #pragma unroll
    for (int off = 8; off; off >>= 1) sc += __shfl_xor(sc, off, 64);  // 16-lane sum
    if (__any(sc > m + 8.f)) {
      float mn = fmaxf(m, sc);
      float scale = __expf(m - mn);
      float w = __expf(sc - mn);
      a0 = fmaf(w, x0, a0 * scale);
      a1 = fmaf(w, x1, a1 * scale);
      d = d * scale + w;
      m = mn;
    } else {
      float w = __expf(sc - m);
      a0 = fmaf(w, x0, a0);
      a1 = fmaf(w, x1, a1);
      d += w;
    }
    xu = xun;
    idxn = idx2;
  }
  // merge the 4 per-group online states (some may be empty; guard via d)
  #pragma unroll
  for (int off = 16; off <= 32; off <<= 1) {
    float mo = __shfl_xor(m, off, 64);
    float doo = __shfl_xor(d, off, 64);
    float c0 = __shfl_xor(a0, off, 64);
    float c1 = __shfl_xor(a1, off, 64);
    if (doo > 0.f) {
      if (d > 0.f) {
        float mn = fmaxf(m, mo);
        float se = __expf(m - mn), so = __expf(mo - mn);
        a0 = a0 * se + c0 * so;
        a1 = a1 * se + c1 * so;
        d = d * se + doo * so;
        m = mn;
      } else {
        a0 = c0; a1 = c1; d = doo; m = mo;
      }
    }
  }
  if (grp == 0) {
    float inv = 1.f / (d + 1e-16f);
    float2 bsv = reinterpret_cast<const float2*>(bias)[cl];
    reinterpret_cast<float2*>(out + (size_t)n * 32)[cl] =
        make_float2(a0 * inv + bsv.x, a1 * inv + bsv.y);
  }
}

extern "C" void kernel_launch(void* const* d_in, const int* in_sizes, int n_in,
                              void* d_out, int out_size, void* d_ws, size_t ws_size,
                              hipStream_t stream) {
  (void)in_sizes; (void)n_in; (void)out_size; (void)ws_size;
  const float* x  = (const float*)d_in[0];
  const int*   ei = (const int*)d_in[1];
  const float *Wl1 = (const float*)d_in[2],  *bl1 = (const float*)d_in[3],
              *Wr1 = (const float*)d_in[4],  *br1 = (const float*)d_in[5],
              *att1 = (const float*)d_in[6], *bias1 = (const float*)d_in[7],
              *g1 = (const float*)d_in[8],   *be1 = (const float*)d_in[9],
              *m1 = (const float*)d_in[10],  *v1 = (const float*)d_in[11];
  const float *Wl2 = (const float*)d_in[12], *bl2 = (const float*)d_in[13],
              *Wr2 = (const float*)d_in[14], *br2 = (const float*)d_in[15],
              *att2 = (const float*)d_in[16], *bias2 = (const float*)d_in[17],
              *g2 = (const float*)d_in[18],  *be2 = (const float*)d_in[19],
              *m2 = (const float*)d_in[20],  *v2 = (const float*)d_in[21];
  const float *Wl3 = (const float*)d_in[22], *bl3 = (const float*)d_in[23],
              *Wr3 = (const float*)d_in[24], *br3 = (const float*)d_in[25],
              *att3 = (const float*)d_in[26], *bias3 = (const float*)d_in[27];
  float* out = (float*)d_out;

  char* p = (char*)d_ws;
  auto alloc = [&](size_t bytes) { char* r = p; p += (bytes + 255) & ~(size_t)255; return r; };
  int*      deg      = (int*)alloc((size_t)NN * 4);
  int*      rowptr   = (int*)alloc((size_t)(NN + 1) * 4);
  int*      cursor   = (int*)alloc((size_t)NN * 4);
  int*      partials = (int*)alloc((size_t)NSCAN * 4);
  int*      csr_src  = (int*)alloc((size_t)ETOT * 4);
  ushort_t* xlr      = (ushort_t*)alloc((size_t)NN * 512 * 2); // interleaved xl|xr
  ushort_t* hbuf     = (ushort_t*)alloc((size_t)NN * 256 * 2);
  ushort_t* Wb       = (ushort_t*)alloc((size_t)147456 * 2);
  (void)alloc(262144);                                         // tail slack (OOB-read room)

  // CSR by dst (2-phase parallel scan)
  hipMemsetAsync(deg, 0, (size_t)NN * 4, stream);
  deg_kernel<<<(ETOT + 255) / 256, 256, 0, stream>>>(ei, deg);
  scan1_kernel<<<NSCAN, 1024, 0, stream>>>(deg, rowptr, partials);
  scan3_kernel<<<NSCAN, 1024, 0, stream>>>(rowptr, partials, cursor);

  int nb = (NN + 3) / 4;

  // ---- CSR fill + layer-1 linear + W2/W3 bf16 conversion (one kernel) ----
  fill_lin1_w2bf<<<FILLB + NN + 576, 256, 0, stream>>>(
      ei, cursor, csr_src, x, Wl1, bl1, Wr1, br1, xlr, Wl2, Wr2, Wl3, Wr3, Wb);
  fused_agg4<true><<<nb, 256, 0, stream>>>(xlr, rowptr, csr_src, att1, bias1,
                                           g1, be1, m1, v1, hbuf);

  // ---- layer 2: 256 -> 4x64 concat (l and r in one N=512 GEMM), BN+ELU ----
  {
    dim3 g((NN + 63) / 64, 2);   // block tile 64 rows x 256 cols (4 waves on N)
    gemm_mfma<512, 256, 1, 4><<<g, 256, 0, stream>>>(hbuf, Wb, bl2, br2, xlr, NN);
  }
  fused_agg4<true><<<nb, 256, 0, stream>>>(xlr, rowptr, csr_src, att2, bias2,
                                           g2, be2, m2, v2, hbuf);

  // ---- layer 3: 256 -> 32, 1 head (l and r in one N=64 GEMM) ----
  {
    dim3 g((NN + 255) / 256, 1); // block tile 256 rows x 64 cols (4 waves on M)
    gemm_mfma<64, 32, 4, 1><<<g, 256, 0, stream>>>(hbuf, Wb + 131072, bl3, br3, xlr, NN);
  }
  fused_agg3<<<nb, 256, 0, stream>>>(xlr, rowptr, csr_src, att3, bias3, out);
}